// Round 9
// baseline (1148.469 us; speedup 1.0000x reference)
//
#include <hip/hip_runtime.h>
#include <stdint.h>

#define KCB 196560   // codebook rows
#define DIM 24       // embed dim
#define BB  2        // batch
#define ZEL 12288    // B*D*16*16

__device__ __forceinline__ unsigned long long pack_key(float sim, int idx) {
  unsigned u = __float_as_uint(sim);
  u = (u & 0x80000000u) ? ~u : (u | 0x80000000u);       // order-preserving float->u32
  return ((unsigned long long)u << 32) | (unsigned)(~(unsigned)idx); // smaller idx wins ties
}

// ---------- init: residual = z, zero the whole output (verbatim) ----------
__global__ __launch_bounds__(256) void init_kernel(const float* __restrict__ z,
    float* __restrict__ residual, float* __restrict__ out, int outTotal) {
  int e = blockIdx.x * 256 + threadIdx.x;
  if (e < ZEL) residual[e] = z[e];
  if (e < outTotal) out[e] = 0.0f;
}

// ---------- downsample residual -> rdown tokens; reset best (verbatim) ----------
__global__ __launch_bounds__(256) void down_kernel(const float* __restrict__ residual,
    float* __restrict__ rdown, unsigned long long* __restrict__ best, int t, int n) {
  int gid = blockIdx.x * 256 + threadIdx.x;
  if (gid < BB * n) best[gid] = 0ull;
  int total = BB * DIM * n;
  if (gid >= total) return;
  int sp = gid % n;
  int d  = (gid / n) % DIM;
  int b  = gid / (n * DIM);
  int oh = sp / t, ow = sp - oh * t;
  float inv_scale = 16.0f / (float)t;
  float ks = inv_scale;
  float sf_h = ((float)oh + 0.5f) * inv_scale - 0.5f;
  float sf_w = ((float)ow + 0.5f) * inv_scale - 0.5f;
  float wh[16], ww[16];
  float sh = 0.f, sw = 0.f;
#pragma unroll
  for (int i = 0; i < 16; ++i) {
    float vh = fmaxf(0.f, 1.f - fabsf(sf_h - (float)i) / ks);
    wh[i] = vh; sh += vh;
    float vw = fmaxf(0.f, 1.f - fabsf(sf_w - (float)i) / ks);
    ww[i] = vw; sw += vw;
  }
#pragma unroll
  for (int i = 0; i < 16; ++i) { wh[i] /= sh; ww[i] /= sw; }
  const float* resb = residual + (b * DIM + d) * 256;
  float acc = 0.f;
  for (int ih = 0; ih < 16; ++ih) {
    float ra = 0.f;
#pragma unroll
    for (int iw = 0; iw < 16; ++iw) ra = fmaf(ww[iw], resb[ih * 16 + iw], ra);
    acc = fmaf(wh[ih], ra, acc);
  }
  rdown[(b * n + sp) * DIM + d] = acc;
}

// ---------- big-T argmax: C=2/lane, rows direct from L2, token-chunk passes ----------
// 4096 waves (1024 blocks) x 48 rows each; pass loop cbase += 128 tokens.
// VGPR budget: tv 48 + ping-pong rows 48 + state ~20 = ~118 <= 512/4 (waves_per_eu 4).
__global__ __attribute__((amdgpu_flat_work_group_size(256, 256),
                          amdgpu_waves_per_eu(4, 4)))
void argmax_direct(const float* __restrict__ cb, const float* __restrict__ rdown,
                   unsigned long long* __restrict__ bb, int T) {
  __shared__ unsigned long long lb[512];
  int tid = threadIdx.x;
  int lane = tid & 63, wv = tid >> 6;
  lb[tid] = 0ull; lb[tid + 256] = 0ull;
  __syncthreads();

  int gw = blockIdx.x * 4 + wv;                 // 4096 waves
  int rBeg = gw * 48;
  int rEnd = min(KCB, rBeg + 48);

  if (rBeg < rEnd) {
    for (int cbase = 0; cbase < T; cbase += 128) {
      int tok[2]; bool valid[2]; float tv[2][DIM];
#pragma unroll
      for (int j = 0; j < 2; ++j) {
        int tt = cbase + j * 64 + lane;
        valid[j] = tt < T;
        tok[j] = valid[j] ? tt : 0;
        const float4* tp = (const float4*)(rdown + tok[j] * DIM);
#pragma unroll
        for (int q = 0; q < 6; ++q) {
          float4 v = tp[q];
          tv[j][q*4+0] = v.x; tv[j][q*4+1] = v.y; tv[j][q*4+2] = v.z; tv[j][q*4+3] = v.w;
        }
      }
      float bs0 = -3.402823466e38f, bs1 = -3.402823466e38f;
      int bi0 = 0, bi1 = 0;

      auto loadRow = [&](float4* buf, int r) {
        const float4* cp = (const float4*)(cb + (size_t)r * DIM);
#pragma unroll
        for (int q = 0; q < 6; ++q) buf[q] = cp[q];
      };
      auto computeRow = [&](const float4* buf, int r) {
        float a0 = 0.f, a1 = 0.f;
#pragma unroll
        for (int q = 0; q < 6; ++q) {           // k-order 0..23 preserved (exact chain)
          a0 = fmaf(tv[0][q*4+0], buf[q].x, a0);
          a0 = fmaf(tv[0][q*4+1], buf[q].y, a0);
          a0 = fmaf(tv[0][q*4+2], buf[q].z, a0);
          a0 = fmaf(tv[0][q*4+3], buf[q].w, a0);
          a1 = fmaf(tv[1][q*4+0], buf[q].x, a1);
          a1 = fmaf(tv[1][q*4+1], buf[q].y, a1);
          a1 = fmaf(tv[1][q*4+2], buf[q].z, a1);
          a1 = fmaf(tv[1][q*4+3], buf[q].w, a1);
        }
        if (a0 > bs0) { bs0 = a0; bi0 = r; }    // strict > keeps lowest idx
        if (a1 > bs1) { bs1 = a1; bi1 = r; }
      };

      float4 A[6], B[6];
      loadRow(A, rBeg);
      for (int r = rBeg; r < rEnd; r += 2) {
        if (r + 1 < rEnd) loadRow(B, r + 1);
        computeRow(A, r);
        if (r + 2 < rEnd) loadRow(A, r + 2);
        if (r + 1 < rEnd) computeRow(B, r + 1);
      }
      if (valid[0]) atomicMax(&lb[tok[0]], pack_key(bs0, bi0));
      if (valid[1]) atomicMax(&lb[tok[1]], pack_key(bs1, bi1));
    }
  }
  __syncthreads();
  for (int t0 = tid; t0 < T; t0 += 256)
    if (lb[t0]) atomicMax(&bb[t0], lb[t0]);
}

// ---------- small-T argmax (verbatim R5 path) ----------
#define RPB 256
__global__ __launch_bounds__(256) void argmax_kernel(const float* __restrict__ cb,
    const float* __restrict__ rdown, unsigned long long* __restrict__ bb, int T) {
  __shared__ float cbT[RPB * DIM];
  __shared__ unsigned long long lb[512];
  int tid = threadIdx.x, blk = blockIdx.x;
  int lane = tid & 63, wv = tid >> 6;
  int rowBase = blk * RPB;
  int rowsHere = min(KCB - rowBase, RPB);
  {
    const float4* s4 = (const float4*)(cb + (size_t)rowBase * DIM);
    float4* d4 = (float4*)cbT;
    int n4 = rowsHere * 6;
    for (int i = tid; i < n4; i += 256) d4[i] = s4[i];
  }
  lb[tid] = 0ull; lb[tid + 256] = 0ull;
  __syncthreads();
  int per = (rowsHere + 3) >> 2;
  int wBeg = min(rowsHere, wv * per);
  int wEnd = min(rowsHere, wBeg + per);

  int tt = lane;
  bool valid = tt < T;
  int tok = valid ? tt : 0;
  float tv[DIM];
  {
    const float4* tp = (const float4*)(rdown + tok * DIM);
#pragma unroll
    for (int q = 0; q < 6; ++q) {
      float4 v = tp[q];
      tv[q*4+0] = v.x; tv[q*4+1] = v.y; tv[q*4+2] = v.z; tv[q*4+3] = v.w;
    }
  }
  float bs = -3.402823466e38f; int bi = 0;
  for (int r = wBeg; r < wEnd; ++r) {
    const float4* cp = (const float4*)(cbT + r * DIM);
    float acc = 0.f;
#pragma unroll
    for (int q = 0; q < 6; ++q) {
      float4 v = cp[q];
      acc = fmaf(tv[q*4+0], v.x, acc);
      acc = fmaf(tv[q*4+1], v.y, acc);
      acc = fmaf(tv[q*4+2], v.z, acc);
      acc = fmaf(tv[q*4+3], v.w, acc);
    }
    int gr = rowBase + r;
    if (acc > bs) { bs = acc; bi = gr; }
  }
  if (valid) atomicMax(&lb[tok], pack_key(bs, bi));
  __syncthreads();
  for (int t0 = tid; t0 < T; t0 += 256)
    if (lb[t0]) atomicMax(&bb[t0], lb[t0]);
}

// ---------- update (verbatim) ----------
template<int TSZ>
__global__ __launch_bounds__(256) void update_kernel(const float* __restrict__ cb,
    const unsigned long long* __restrict__ best, float* __restrict__ residual,
    float* __restrict__ out, int idxBase) {
  constexpr int N = TSZ * TSZ;
  constexpr int T = BB * N;
  __shared__ float zq[T * DIM];
  int tid = threadIdx.x;
  for (int slot = tid; slot < T; slot += 256) {
    unsigned long long key = best[slot];
    int idx = (int)(~(unsigned)key);
    const float* cv = cb + (long long)idx * DIM;
    float v[DIM]; float ss = 0.f;
#pragma unroll
    for (int k = 0; k < DIM; ++k) { v[k] = cv[k]; ss = fmaf(v[k], v[k], ss); }
    float nrm = sqrtf(ss);
#pragma unroll
    for (int k = 0; k < DIM; ++k) zq[slot * DIM + k] = v[k] / nrm;
    if (blockIdx.x == 0) out[idxBase + slot] = (float)idx;
  }
  __syncthreads();
  int e = blockIdx.x * 256 + tid;
  int w = e & 15, h = (e >> 4) & 15;
  int d = (e >> 8) % DIM;
  int b = e / (DIM * 256);
  float inv_scale = (float)TSZ / 16.0f;
  float sf_h = ((float)h + 0.5f) * inv_scale - 0.5f;
  float sf_w = ((float)w + 0.5f) * inv_scale - 0.5f;
  float wh[TSZ], ww[TSZ];
  float sh = 0.f, sw = 0.f;
#pragma unroll
  for (int j = 0; j < TSZ; ++j) {
    float vh = fmaxf(0.f, 1.f - fabsf(sf_h - (float)j));
    wh[j] = vh; sh += vh;
    float vw = fmaxf(0.f, 1.f - fabsf(sf_w - (float)j));
    ww[j] = vw; sw += vw;
  }
#pragma unroll
  for (int j = 0; j < TSZ; ++j) { wh[j] /= sh; ww[j] /= sw; }
  const float* zb = zq + (b * N) * DIM + d;
  float acc = 0.f;
#pragma unroll
  for (int th = 0; th < TSZ; ++th) {
    float ra = 0.f;
#pragma unroll
    for (int tw = 0; tw < TSZ; ++tw) ra = fmaf(ww[tw], zb[(th * TSZ + tw) * DIM], ra);
    acc = fmaf(wh[th], ra, acc);
  }
  out[e] += acc;
  residual[e] -= acc;
}

// ---------- host ----------
extern "C" void kernel_launch(void* const* d_in, const int* in_sizes, int n_in,
                              void* d_out, int out_size, void* d_ws, size_t ws_size,
                              hipStream_t stream) {
  const float* z  = (const float*)d_in[0];
  const float* cb = (const float*)d_in[1];
  float* out = (float*)d_out;
  float* residual = (float*)d_ws;                          // 12288 f
  float* rdown = residual + ZEL;                           // 12288 f
  unsigned long long* best =
      (unsigned long long*)((char*)d_ws + 2 * ZEL * sizeof(float)); // 512 u64 (proven footprint)

  static const int TS[10] = {1, 2, 3, 4, 5, 6, 8, 10, 13, 16};

  init_kernel<<<(out_size + 255) / 256, 256, 0, stream>>>(z, residual, out, out_size);

  int prefix = 0;
  for (int s = 0; s < 10; ++s) {
    int t = TS[s], n = t * t, T = BB * n;
    int dtotal = BB * DIM * n;
    down_kernel<<<(dtotal + 255) / 256, 256, 0, stream>>>(residual, rdown, best, t, n);

    if (T > 64) argmax_direct<<<1024, 256, 0, stream>>>(cb, rdown, best, T);
    else        argmax_kernel<<<768, 256, 0, stream>>>(cb, rdown, best, T);

    int idxBase = ZEL + BB * prefix;
    switch (t) {
      case 1:  update_kernel<1><<<48, 256, 0, stream>>>(cb, best, residual, out, idxBase); break;
      case 2:  update_kernel<2><<<48, 256, 0, stream>>>(cb, best, residual, out, idxBase); break;
      case 3:  update_kernel<3><<<48, 256, 0, stream>>>(cb, best, residual, out, idxBase); break;
      case 4:  update_kernel<4><<<48, 256, 0, stream>>>(cb, best, residual, out, idxBase); break;
      case 5:  update_kernel<5><<<48, 256, 0, stream>>>(cb, best, residual, out, idxBase); break;
      case 6:  update_kernel<6><<<48, 256, 0, stream>>>(cb, best, residual, out, idxBase); break;
      case 8:  update_kernel<8><<<48, 256, 0, stream>>>(cb, best, residual, out, idxBase); break;
      case 10: update_kernel<10><<<48, 256, 0, stream>>>(cb, best, residual, out, idxBase); break;
      case 13: update_kernel<13><<<48, 256, 0, stream>>>(cb, best, residual, out, idxBase); break;
      case 16: update_kernel<16><<<48, 256, 0, stream>>>(cb, best, residual, out, idxBase); break;
    }
    prefix += n;
  }
}

// Round 10
// 720.715 us; speedup vs baseline: 1.5935x; 1.5935x over previous
//
#include <hip/hip_runtime.h>
#include <stdint.h>

#define KCB 196560   // codebook rows
#define DIM 24       // embed dim
#define BB  2        // batch
#define ZEL 12288    // B*D*16*16

__device__ __forceinline__ unsigned long long pack_key(float sim, int idx) {
  unsigned u = __float_as_uint(sim);
  u = (u & 0x80000000u) ? ~u : (u | 0x80000000u);       // order-preserving float->u32
  return ((unsigned long long)u << 32) | (unsigned)(~(unsigned)idx); // smaller idx wins ties
}

// ---------- init: residual = z, zero the whole output (verbatim) ----------
__global__ __launch_bounds__(256) void init_kernel(const float* __restrict__ z,
    float* __restrict__ residual, float* __restrict__ out, int outTotal) {
  int e = blockIdx.x * 256 + threadIdx.x;
  if (e < ZEL) residual[e] = z[e];
  if (e < outTotal) out[e] = 0.0f;
}

// ---------- downsample residual -> rdown tokens; reset best (verbatim) ----------
__global__ __launch_bounds__(256) void down_kernel(const float* __restrict__ residual,
    float* __restrict__ rdown, unsigned long long* __restrict__ best, int t, int n) {
  int gid = blockIdx.x * 256 + threadIdx.x;
  if (gid < BB * n) best[gid] = 0ull;
  int total = BB * DIM * n;
  if (gid >= total) return;
  int sp = gid % n;
  int d  = (gid / n) % DIM;
  int b  = gid / (n * DIM);
  int oh = sp / t, ow = sp - oh * t;
  float inv_scale = 16.0f / (float)t;
  float ks = inv_scale;
  float sf_h = ((float)oh + 0.5f) * inv_scale - 0.5f;
  float sf_w = ((float)ow + 0.5f) * inv_scale - 0.5f;
  float wh[16], ww[16];
  float sh = 0.f, sw = 0.f;
#pragma unroll
  for (int i = 0; i < 16; ++i) {
    float vh = fmaxf(0.f, 1.f - fabsf(sf_h - (float)i) / ks);
    wh[i] = vh; sh += vh;
    float vw = fmaxf(0.f, 1.f - fabsf(sf_w - (float)i) / ks);
    ww[i] = vw; sw += vw;
  }
#pragma unroll
  for (int i = 0; i < 16; ++i) { wh[i] /= sh; ww[i] /= sw; }
  const float* resb = residual + (b * DIM + d) * 256;
  float acc = 0.f;
  for (int ih = 0; ih < 16; ++ih) {
    float ra = 0.f;
#pragma unroll
    for (int iw = 0; iw < 16; ++iw) ra = fmaf(ww[iw], resb[ih * 16 + iw], ra);
    acc = fmaf(wh[ih], ra, acc);
  }
  rdown[(b * n + sp) * DIM + d] = acc;
}

// ---------- big-T argmax: C=2/lane, rows direct from global/L2 ----------
// Designed for <=~64 live VGPRs (allocator refuses more: R5-R9 evidence).
// 4096 waves x 48 rows; token passes cbase += 128. Row loads are wave-uniform
// float4 (broadcast, VMEM pipe); no LDS in hot loop; no ping-pong buffers --
// latency hidden by 4 waves/SIMD occupancy instead of registers.
__global__ __launch_bounds__(256) void argmax_direct(const float* __restrict__ cb,
    const float* __restrict__ rdown, unsigned long long* __restrict__ bb, int T) {
  __shared__ unsigned long long lb[512];
  int tid = threadIdx.x;
  int lane = tid & 63, wv = tid >> 6;
  lb[tid] = 0ull; lb[tid + 256] = 0ull;
  __syncthreads();

  int gw = blockIdx.x * 4 + wv;                 // 4096 waves
  int rBeg = gw * 48;
  int rEnd = min(KCB, rBeg + 48);

  for (int cbase = 0; cbase < T; cbase += 128) {
    int t0 = cbase + lane;
    int t1 = cbase + 64 + lane;
    bool v0 = t0 < T, v1 = t1 < T;
    int k0 = v0 ? t0 : 0, k1 = v1 ? t1 : 0;
    float tv0[DIM], tv1[DIM];
    {
      const float4* tp0 = (const float4*)(rdown + k0 * DIM);
      const float4* tp1 = (const float4*)(rdown + k1 * DIM);
#pragma unroll
      for (int q = 0; q < 6; ++q) {
        float4 a = tp0[q];
        tv0[q*4+0] = a.x; tv0[q*4+1] = a.y; tv0[q*4+2] = a.z; tv0[q*4+3] = a.w;
        float4 b = tp1[q];
        tv1[q*4+0] = b.x; tv1[q*4+1] = b.y; tv1[q*4+2] = b.z; tv1[q*4+3] = b.w;
      }
    }
    float bs0 = -3.402823466e38f, bs1 = -3.402823466e38f;
    int bi0 = 0, bi1 = 0;
    if (rBeg < rEnd) {
      const float4* cp = (const float4*)(cb + (size_t)rBeg * DIM);
      for (int r = rBeg; r < rEnd; ++r, cp += 6) {
        float a0 = 0.f, a1 = 0.f;
#pragma unroll
        for (int q = 0; q < 6; ++q) {           // k-order 0..23 preserved (exact chain)
          float4 v = cp[q];
          a0 = fmaf(tv0[q*4+0], v.x, a0);
          a0 = fmaf(tv0[q*4+1], v.y, a0);
          a0 = fmaf(tv0[q*4+2], v.z, a0);
          a0 = fmaf(tv0[q*4+3], v.w, a0);
          a1 = fmaf(tv1[q*4+0], v.x, a1);
          a1 = fmaf(tv1[q*4+1], v.y, a1);
          a1 = fmaf(tv1[q*4+2], v.z, a1);
          a1 = fmaf(tv1[q*4+3], v.w, a1);
        }
        if (a0 > bs0) { bs0 = a0; bi0 = r; }    // strict > keeps lowest idx
        if (a1 > bs1) { bs1 = a1; bi1 = r; }
      }
      if (v0) atomicMax(&lb[t0], pack_key(bs0, bi0));
      if (v1) atomicMax(&lb[t1], pack_key(bs1, bi1));
    }
  }
  __syncthreads();
  for (int s = tid; s < T; s += 256) {
    unsigned long long k = lb[s];
    if (k && k > bb[s]) atomicMax(&bb[s], k);   // bb monotonic -> pre-check safe
  }
}

// ---------- small-T argmax (verbatim R9 path) ----------
#define RPB 256
__global__ __launch_bounds__(256) void argmax_kernel(const float* __restrict__ cb,
    const float* __restrict__ rdown, unsigned long long* __restrict__ bb, int T) {
  __shared__ float cbT[RPB * DIM];
  __shared__ unsigned long long lb[512];
  int tid = threadIdx.x, blk = blockIdx.x;
  int lane = tid & 63, wv = tid >> 6;
  int rowBase = blk * RPB;
  int rowsHere = min(KCB - rowBase, RPB);
  {
    const float4* s4 = (const float4*)(cb + (size_t)rowBase * DIM);
    float4* d4 = (float4*)cbT;
    int n4 = rowsHere * 6;
    for (int i = tid; i < n4; i += 256) d4[i] = s4[i];
  }
  lb[tid] = 0ull; lb[tid + 256] = 0ull;
  __syncthreads();
  int per = (rowsHere + 3) >> 2;
  int wBeg = min(rowsHere, wv * per);
  int wEnd = min(rowsHere, wBeg + per);

  int tt = lane;
  bool valid = tt < T;
  int tok = valid ? tt : 0;
  float tv[DIM];
  {
    const float4* tp = (const float4*)(rdown + tok * DIM);
#pragma unroll
    for (int q = 0; q < 6; ++q) {
      float4 v = tp[q];
      tv[q*4+0] = v.x; tv[q*4+1] = v.y; tv[q*4+2] = v.z; tv[q*4+3] = v.w;
    }
  }
  float bs = -3.402823466e38f; int bi = 0;
  for (int r = wBeg; r < wEnd; ++r) {
    const float4* cp = (const float4*)(cbT + r * DIM);
    float acc = 0.f;
#pragma unroll
    for (int q = 0; q < 6; ++q) {
      float4 v = cp[q];
      acc = fmaf(tv[q*4+0], v.x, acc);
      acc = fmaf(tv[q*4+1], v.y, acc);
      acc = fmaf(tv[q*4+2], v.z, acc);
      acc = fmaf(tv[q*4+3], v.w, acc);
    }
    int gr = rowBase + r;
    if (acc > bs) { bs = acc; bi = gr; }
  }
  if (valid) atomicMax(&lb[tok], pack_key(bs, bi));
  __syncthreads();
  for (int t0 = tid; t0 < T; t0 += 256)
    if (lb[t0]) atomicMax(&bb[t0], lb[t0]);
}

// ---------- update (verbatim) ----------
template<int TSZ>
__global__ __launch_bounds__(256) void update_kernel(const float* __restrict__ cb,
    const unsigned long long* __restrict__ best, float* __restrict__ residual,
    float* __restrict__ out, int idxBase) {
  constexpr int N = TSZ * TSZ;
  constexpr int T = BB * N;
  __shared__ float zq[T * DIM];
  int tid = threadIdx.x;
  for (int slot = tid; slot < T; slot += 256) {
    unsigned long long key = best[slot];
    int idx = (int)(~(unsigned)key);
    const float* cv = cb + (long long)idx * DIM;
    float v[DIM]; float ss = 0.f;
#pragma unroll
    for (int k = 0; k < DIM; ++k) { v[k] = cv[k]; ss = fmaf(v[k], v[k], ss); }
    float nrm = sqrtf(ss);
#pragma unroll
    for (int k = 0; k < DIM; ++k) zq[slot * DIM + k] = v[k] / nrm;
    if (blockIdx.x == 0) out[idxBase + slot] = (float)idx;
  }
  __syncthreads();
  int e = blockIdx.x * 256 + tid;
  int w = e & 15, h = (e >> 4) & 15;
  int d = (e >> 8) % DIM;
  int b = e / (DIM * 256);
  float inv_scale = (float)TSZ / 16.0f;
  float sf_h = ((float)h + 0.5f) * inv_scale - 0.5f;
  float sf_w = ((float)w + 0.5f) * inv_scale - 0.5f;
  float wh[TSZ], ww[TSZ];
  float sh = 0.f, sw = 0.f;
#pragma unroll
  for (int j = 0; j < TSZ; ++j) {
    float vh = fmaxf(0.f, 1.f - fabsf(sf_h - (float)j));
    wh[j] = vh; sh += vh;
    float vw = fmaxf(0.f, 1.f - fabsf(sf_w - (float)j));
    ww[j] = vw; sw += vw;
  }
#pragma unroll
  for (int j = 0; j < TSZ; ++j) { wh[j] /= sh; ww[j] /= sw; }
  const float* zb = zq + (b * N) * DIM + d;
  float acc = 0.f;
#pragma unroll
  for (int th = 0; th < TSZ; ++th) {
    float ra = 0.f;
#pragma unroll
    for (int tw = 0; tw < TSZ; ++tw) ra = fmaf(ww[tw], zb[(th * TSZ + tw) * DIM], ra);
    acc = fmaf(wh[th], ra, acc);
  }
  out[e] += acc;
  residual[e] -= acc;
}

// ---------- host ----------
extern "C" void kernel_launch(void* const* d_in, const int* in_sizes, int n_in,
                              void* d_out, int out_size, void* d_ws, size_t ws_size,
                              hipStream_t stream) {
  const float* z  = (const float*)d_in[0];
  const float* cb = (const float*)d_in[1];
  float* out = (float*)d_out;
  float* residual = (float*)d_ws;                          // 12288 f
  float* rdown = residual + ZEL;                           // 12288 f
  unsigned long long* best =
      (unsigned long long*)((char*)d_ws + 2 * ZEL * sizeof(float)); // 512 u64 (proven footprint)

  static const int TS[10] = {1, 2, 3, 4, 5, 6, 8, 10, 13, 16};

  init_kernel<<<(out_size + 255) / 256, 256, 0, stream>>>(z, residual, out, out_size);

  int prefix = 0;
  for (int s = 0; s < 10; ++s) {
    int t = TS[s], n = t * t, T = BB * n;
    int dtotal = BB * DIM * n;
    down_kernel<<<(dtotal + 255) / 256, 256, 0, stream>>>(residual, rdown, best, t, n);

    if (T > 64) argmax_direct<<<1024, 256, 0, stream>>>(cb, rdown, best, T);
    else        argmax_kernel<<<768, 256, 0, stream>>>(cb, rdown, best, T);

    int idxBase = ZEL + BB * prefix;
    switch (t) {
      case 1:  update_kernel<1><<<48, 256, 0, stream>>>(cb, best, residual, out, idxBase); break;
      case 2:  update_kernel<2><<<48, 256, 0, stream>>>(cb, best, residual, out, idxBase); break;
      case 3:  update_kernel<3><<<48, 256, 0, stream>>>(cb, best, residual, out, idxBase); break;
      case 4:  update_kernel<4><<<48, 256, 0, stream>>>(cb, best, residual, out, idxBase); break;
      case 5:  update_kernel<5><<<48, 256, 0, stream>>>(cb, best, residual, out, idxBase); break;
      case 6:  update_kernel<6><<<48, 256, 0, stream>>>(cb, best, residual, out, idxBase); break;
      case 8:  update_kernel<8><<<48, 256, 0, stream>>>(cb, best, residual, out, idxBase); break;
      case 10: update_kernel<10><<<48, 256, 0, stream>>>(cb, best, residual, out, idxBase); break;
      case 13: update_kernel<13><<<48, 256, 0, stream>>>(cb, best, residual, out, idxBase); break;
      case 16: update_kernel<16><<<48, 256, 0, stream>>>(cb, best, residual, out, idxBase); break;
    }
    prefix += n;
  }
}